// Round 22
// baseline (54.102 us; speedup 1.0000x reference)
//
#include <hip/hip_runtime.h>

// GCN layer: out = relu( G(feature) @ W^T + b ), G = mean over in-edges (or
// identity for isolated nodes).  N=50000, F=64, E=800000.
//
// GEMM commutes with the aggregation: G(feat)@W^T == G(feat@W^T).
// Round-22: GEMM-role LDS-ratio fix. Old: 2 nodes/thread, 3 LDS reads per
// 8 FMA (LDS-pipe bound ~15us across 1563 blocks). New: 64 nodes/block
// (G=782), shh TRANSPOSED [k][node] (pad 68), thread=(nquad,foq) holds
// 4 nodes x 4 feats in float4 regs -> 2x ds_read_b128 per 16 FMA, and W
// staging traffic halves. k_bingather unchanged (clean attribution).
// Pipeline (2 dispatches): k_work (GEMM || quarter-sort) -> k_bingather.

#define F 64
#define CAP 48          // bucket slots per node
#define QW 64           // nodes per quarter (bin granularity)
#define EB 2048         // edges per shard block
#define OVF_MAX 32768

typedef unsigned int uint;
typedef unsigned short ushort;

__device__ __forceinline__ ushort f2bf(float x) {
    uint u = __float_as_uint(x);
    u += 0x7FFFu + ((u >> 16) & 1u);   // round-to-nearest-even
    return (ushort)(u >> 16);
}

// ---------- D1: role-split GEMM + quarter-sort ----------
__global__ __launch_bounds__(256) void k_work(const float* __restrict__ feature,
                                              const float* __restrict__ W,
                                              ushort* __restrict__ Ybf,
                                              const int* __restrict__ esrc,
                                              const int* __restrict__ edst,
                                              int* __restrict__ blkBuf,
                                              int* __restrict__ pfxTab,
                                              int* __restrict__ ovfB,
                                              int N, int E, int G, int QP1) {
    __shared__ alignas(16) char smem[36864];
    int tid = threadIdx.x, bid = blockIdx.x;
    if (bid == 0 && tid == 0) ovfB[0] = 0;

    if (bid < G) {
        // ---- GEMM role: 64 nodes/block, transposed h staging ----
        float* sWt = (float*)smem;              // 64k x 76 pad: 19456B
        float* shh = (float*)(smem + 19456);    // 64k x 68 pad: 17408B (shh[k][n])
        for (int i = tid; i < 4096; i += 256) {
            int fo = i >> 6, k = i & 63;
            sWt[k * 76 + fo] = W[i];            // sWt[k][fo]
        }
        int n0blk = bid * 64;
        for (int i = tid; i < 1024; i += 256) { // 64 nodes x 16 float4
            int nl = i >> 4, c4 = i & 15;
            int n = n0blk + nl;
            float4 v = make_float4(0.f, 0.f, 0.f, 0.f);
            if (n < N) v = ((const float4*)feature)[(long)n * 16 + c4];
            shh[(c4 * 4 + 0) * 68 + nl] = v.x;  // transpose: shh[k][node]
            shh[(c4 * 4 + 1) * 68 + nl] = v.y;
            shh[(c4 * 4 + 2) * 68 + nl] = v.z;
            shh[(c4 * 4 + 3) * 68 + nl] = v.w;
        }
        __syncthreads();
        int nq = tid >> 4, foq = tid & 15;      // 4 nodes, 4 out-feats each
        float4 r0 = make_float4(0.f,0.f,0.f,0.f), r1 = r0, r2 = r0, r3 = r0;
#pragma unroll 8
        for (int k = 0; k < 64; ++k) {
            float4 h  = *(const float4*)&shh[k * 68 + nq * 4];
            float4 wv = *(const float4*)&sWt[k * 76 + foq * 4];
            r0.x = fmaf(h.x, wv.x, r0.x); r0.y = fmaf(h.x, wv.y, r0.y);
            r0.z = fmaf(h.x, wv.z, r0.z); r0.w = fmaf(h.x, wv.w, r0.w);
            r1.x = fmaf(h.y, wv.x, r1.x); r1.y = fmaf(h.y, wv.y, r1.y);
            r1.z = fmaf(h.y, wv.z, r1.z); r1.w = fmaf(h.y, wv.w, r1.w);
            r2.x = fmaf(h.z, wv.x, r2.x); r2.y = fmaf(h.z, wv.y, r2.y);
            r2.z = fmaf(h.z, wv.z, r2.z); r2.w = fmaf(h.z, wv.w, r2.w);
            r3.x = fmaf(h.w, wv.x, r3.x); r3.y = fmaf(h.w, wv.y, r3.y);
            r3.z = fmaf(h.w, wv.z, r3.z); r3.w = fmaf(h.w, wv.w, r3.w);
        }
        int nb = n0blk + nq * 4;
        if (nb + 0 < N) ((ushort4*)Ybf)[(long)(nb + 0) * 16 + foq] =
            make_ushort4(f2bf(r0.x), f2bf(r0.y), f2bf(r0.z), f2bf(r0.w));
        if (nb + 1 < N) ((ushort4*)Ybf)[(long)(nb + 1) * 16 + foq] =
            make_ushort4(f2bf(r1.x), f2bf(r1.y), f2bf(r1.z), f2bf(r1.w));
        if (nb + 2 < N) ((ushort4*)Ybf)[(long)(nb + 2) * 16 + foq] =
            make_ushort4(f2bf(r2.x), f2bf(r2.y), f2bf(r2.z), f2bf(r2.w));
        if (nb + 3 < N) ((ushort4*)Ybf)[(long)(nb + 3) * 16 + foq] =
            make_ushort4(f2bf(r3.x), f2bf(r3.y), f2bf(r3.z), f2bf(r3.w));
    } else {
        // ---- sort role: 2048 edges binned by quarter (dst>>6) ----
        int* cnt   = (int*)smem;                // 1024 ints
        int* pfx   = (int*)(smem + 4096);       // 1024 ints
        int* off   = (int*)(smem + 8192);       // 1024 ints
        int* sc    = (int*)(smem + 12288);      // 256 ints
        int* stage = (int*)(smem + 13312);      // 2048 ints

        int b = bid - G;
        int ebase = b * EB;
        int d[8], s[8];
        int i0 = ebase + tid * 8;
        if (i0 + 7 < E) {
            int4 a  = *(const int4*)(edst + i0);
            int4 b4 = *(const int4*)(edst + i0 + 4);
            d[0]=a.x; d[1]=a.y; d[2]=a.z; d[3]=a.w;
            d[4]=b4.x; d[5]=b4.y; d[6]=b4.z; d[7]=b4.w;
            int4 c4 = *(const int4*)(esrc + i0);
            int4 e4 = *(const int4*)(esrc + i0 + 4);
            s[0]=c4.x; s[1]=c4.y; s[2]=c4.z; s[3]=c4.w;
            s[4]=e4.x; s[5]=e4.y; s[6]=e4.z; s[7]=e4.w;
        } else {
#pragma unroll
            for (int k = 0; k < 8; ++k) {
                int e = i0 + k;
                d[k] = (e < E) ? edst[e] : -1;
                s[k] = (e < E) ? esrc[e] : 0;
            }
        }
        for (int i = tid; i < 1024; i += 256) cnt[i] = 0;
        __syncthreads();
#pragma unroll
        for (int k = 0; k < 8; ++k)
            if (d[k] >= 0) atomicAdd(&cnt[d[k] >> 6], 1);
        __syncthreads();
        // two-level exclusive scan over 1024 bins (4 bins/thread)
        int b0i = tid * 4;
        int c0 = cnt[b0i], c1 = cnt[b0i+1], c2 = cnt[b0i+2], c3 = cnt[b0i+3];
        int s4 = c0 + c1 + c2 + c3;
        sc[tid] = s4;
        __syncthreads();
        for (int dd = 1; dd < 256; dd <<= 1) {
            int t = (tid >= dd) ? sc[tid - dd] : 0;
            __syncthreads();
            sc[tid] += t;
            __syncthreads();
        }
        int run = sc[tid] - s4;
        pfx[b0i]   = run; off[b0i]   = run; run += c0;
        pfx[b0i+1] = run; off[b0i+1] = run; run += c1;
        pfx[b0i+2] = run; off[b0i+2] = run; run += c2;
        pfx[b0i+3] = run; off[b0i+3] = run;
        __syncthreads();
#pragma unroll
        for (int k = 0; k < 8; ++k) {
            if (d[k] >= 0) {
                int q = d[k] >> 6;
                int sl = atomicAdd(&off[q], 1);
                stage[sl] = ((d[k] & 63) << 24) | s[k];   // N<=65536 (host guard)
            }
        }
        __syncthreads();
        int total = sc[255];
        for (int i = tid; i < total; i += 256)
            blkBuf[ebase + i] = stage[i];                 // coalesced dump
        for (int i = tid; i < QP1; i += 256)
            pfxTab[b * QP1 + i] = pfx[i];                 // bins >= Q hold total
    }
}

// ---------- D2: per-quarter bin (LDS) + gather-mean + bias + relu ----------
__global__ __launch_bounds__(512) void k_bingather(const ushort* __restrict__ Ybf,
                                                   const int* __restrict__ blkBuf,
                                                   const int* __restrict__ pfxTab,
                                                   int* __restrict__ ovfB,
                                                   const float* __restrict__ bias,
                                                   float* __restrict__ out,
                                                   int N, int S, int QP1) {
    __shared__ int dl[QW];
    __shared__ int bl[QW * CAP];   // 12.3KB
    int tid = threadIdx.x;
    int q   = blockIdx.x;          // quarter id: nodes q*64 .. q*64+63
    for (int i = tid; i < QW; i += 512) dl[i] = 0;
    __syncthreads();
    // bin: one thread per source block's run (exact entries, no filtering)
    for (int b = tid; b < S; b += 512) {
        int lo = pfxTab[b * QP1 + q];
        int hi = pfxTab[b * QP1 + q + 1];
        for (int i = lo; i < hi; ++i) {
            int v = blkBuf[b * EB + i];
            int ll = ((uint)v) >> 24;
            int s = v & 0xFFFFFF;
            int r = atomicAdd(&dl[ll], 1);
            if (r < CAP) bl[ll * CAP + r] = s;
            else { int o = atomicAdd(&ovfB[0], 1);
                   if (o < OVF_MAX) { ovfB[2 + 2*o] = q * QW + ll; ovfB[3 + 2*o] = s; } }
        }
    }
    __syncthreads();
    // gather: 8 waves x 8 passes = 64 nodes; 16-edge stride, 2 chains
    int wv = tid >> 6, lane = tid & 63;
    int g = lane >> 3, c = lane & 7;
    const uint4* Y16 = (const uint4*)Ybf;
    for (int pass = 0; pass < QW / 8; ++pass) {
        int ll = pass * 8 + wv;
        int n = q * QW + ll;
        if (n < N) {
            int d = dl[ll];
            int m = min(d, CAP);
            float acc[2][8];
#pragma unroll
            for (int ch = 0; ch < 2; ++ch)
#pragma unroll
                for (int j = 0; j < 8; ++j) acc[ch][j] = 0.f;
            int last = m - 1;
            for (int base = 0; base < m; base += 16) {
#pragma unroll
                for (int ch = 0; ch < 2; ++ch) {
                    int jdx = base + ch * 8 + g;
                    int s = bl[ll * CAP + min(jdx, last)];
                    uint4 qv = Y16[(long)s * 8 + c];
                    if (jdx < m) {
                        acc[ch][0] += __uint_as_float(qv.x << 16);
                        acc[ch][1] += __uint_as_float(qv.x & 0xFFFF0000u);
                        acc[ch][2] += __uint_as_float(qv.y << 16);
                        acc[ch][3] += __uint_as_float(qv.y & 0xFFFF0000u);
                        acc[ch][4] += __uint_as_float(qv.z << 16);
                        acc[ch][5] += __uint_as_float(qv.z & 0xFFFF0000u);
                        acc[ch][6] += __uint_as_float(qv.w << 16);
                        acc[ch][7] += __uint_as_float(qv.w & 0xFFFF0000u);
                    }
                }
            }
            if (d > CAP) {   // overflow tail (empty for this input)
                int no = ovfB[0]; if (no > OVF_MAX) no = OVF_MAX;
                if (g == 0) {
                    for (int i = 0; i < no; ++i) {
                        if (ovfB[2 + 2*i] == n) {
                            int s = ovfB[3 + 2*i];
                            uint4 qv = Y16[(long)s * 8 + c];
                            acc[0][0] += __uint_as_float(qv.x << 16);
                            acc[0][1] += __uint_as_float(qv.x & 0xFFFF0000u);
                            acc[0][2] += __uint_as_float(qv.y << 16);
                            acc[0][3] += __uint_as_float(qv.y & 0xFFFF0000u);
                            acc[0][4] += __uint_as_float(qv.z << 16);
                            acc[0][5] += __uint_as_float(qv.z & 0xFFFF0000u);
                            acc[0][6] += __uint_as_float(qv.w << 16);
                            acc[0][7] += __uint_as_float(qv.w & 0xFFFF0000u);
                        }
                    }
                }
            }
#pragma unroll
            for (int j = 0; j < 8; ++j)
                acc[0][j] += acc[1][j];
#pragma unroll
            for (int j = 0; j < 8; ++j) {
                float v = acc[0][j];
                v += __shfl_xor(v, 8);
                v += __shfl_xor(v, 16);
                v += __shfl_xor(v, 32);
                acc[0][j] = v;
            }
            float sel = acc[0][0];
#pragma unroll
            for (int j = 1; j < 8; ++j) sel = (g == j) ? acc[0][j] : sel;
            int fw = c * 8 + g;
            float hv;
            if (d > 0) hv = sel / (float)d;
            else       hv = __uint_as_float(((uint)Ybf[(long)n * F + fw]) << 16);
            out[(long)n * F + fw] = fmaxf(hv + bias[fw], 0.0f);
        }
    }
}

// ================= mid-tier (R13/R16 proven) ==========================
__global__ __launch_bounds__(256) void k_gemm13(const float* __restrict__ feature,
                                                const float* __restrict__ W,
                                                ushort* __restrict__ Ybf, int N,
                                                int* __restrict__ deg, int n4,
                                                int* __restrict__ ovfB) {
    {
        int gt = blockIdx.x * 256 + threadIdx.x;
        if (gt == 0) ovfB[0] = 0;
        for (int i = gt; i < n4; i += gridDim.x * 256)
            ((int4*)deg)[i] = make_int4(0, 0, 0, 0);
    }
    __shared__ float sWt[64 * 76];
    __shared__ float shh[32 * 72];
    int tid = threadIdx.x;
    for (int i = tid; i < 4096; i += 256) {
        int fo = i >> 6, k = i & 63;
        sWt[k * 76 + fo] = W[i];
    }
    int n0blk = blockIdx.x * 32;
    for (int i = tid; i < 512; i += 256) {
        int r = i >> 4, c4 = i & 15;
        int n = n0blk + r;
        float4 v = make_float4(0.f, 0.f, 0.f, 0.f);
        if (n < N) v = ((const float4*)feature)[(long)n * 16 + c4];
        *(float4*)&shh[r * 72 + c4 * 4] = v;
    }
    __syncthreads();
    int npair = tid >> 4, foq = tid & 15;
    int r0 = npair * 2, r1 = r0 + 1;
    float a0=0,a1=0,a2=0,a3=0,b0=0,b1=0,b2=0,b3=0;
#pragma unroll 8
    for (int k = 0; k < 64; ++k) {
        float hA = shh[r0 * 72 + k];
        float hB = shh[r1 * 72 + k];
        float4 wv = *(const float4*)&sWt[k * 76 + foq * 4];
        a0 = fmaf(hA, wv.x, a0); a1 = fmaf(hA, wv.y, a1);
        a2 = fmaf(hA, wv.z, a2); a3 = fmaf(hA, wv.w, a3);
        b0 = fmaf(hB, wv.x, b0); b1 = fmaf(hB, wv.y, b1);
        b2 = fmaf(hB, wv.z, b2); b3 = fmaf(hB, wv.w, b3);
    }
    int nA = n0blk + r0, nB = n0blk + r1;
    if (nA < N) ((ushort4*)Ybf)[(long)nA * 16 + foq] =
        make_ushort4(f2bf(a0), f2bf(a1), f2bf(a2), f2bf(a3));
    if (nB < N) ((ushort4*)Ybf)[(long)nB * 16 + foq] =
        make_ushort4(f2bf(b0), f2bf(b1), f2bf(b2), f2bf(b3));
}

__global__ __launch_bounds__(256) void k_scatter13(const int* __restrict__ esrc,
                                                   const int* __restrict__ edst,
                                                   int* __restrict__ deg,
                                                   int* __restrict__ bucket,
                                                   int* __restrict__ ovfB, int E) {
    int base = (blockIdx.x * 256 + threadIdx.x) * 4;
    if (base + 3 < E) {
        int4 d4 = *(const int4*)(edst + base);
        int4 s4 = *(const int4*)(esrc + base);
        int r0 = atomicAdd(&deg[d4.x], 1);
        int r1 = atomicAdd(&deg[d4.y], 1);
        int r2 = atomicAdd(&deg[d4.z], 1);
        int r3 = atomicAdd(&deg[d4.w], 1);
        if (r0 < CAP) bucket[d4.x * CAP + r0] = s4.x;
        else { int o = atomicAdd(&ovfB[0], 1); if (o < OVF_MAX) { ovfB[2 + 2*o] = d4.x; ovfB[3 + 2*o] = s4.x; } }
        if (r1 < CAP) bucket[d4.y * CAP + r1] = s4.y;
        else { int o = atomicAdd(&ovfB[0], 1); if (o < OVF_MAX) { ovfB[2 + 2*o] = d4.y; ovfB[3 + 2*o] = s4.y; } }
        if (r2 < CAP) bucket[d4.z * CAP + r2] = s4.z;
        else { int o = atomicAdd(&ovfB[0], 1); if (o < OVF_MAX) { ovfB[2 + 2*o] = d4.z; ovfB[3 + 2*o] = s4.z; } }
        if (r3 < CAP) bucket[d4.w * CAP + r3] = s4.w;
        else { int o = atomicAdd(&ovfB[0], 1); if (o < OVF_MAX) { ovfB[2 + 2*o] = d4.w; ovfB[3 + 2*o] = s4.w; } }
    } else {
        for (int e = base; e < E; ++e) {
            int d = edst[e], s = esrc[e];
            int r = atomicAdd(&deg[d], 1);
            if (r < CAP) bucket[d * CAP + r] = s;
            else { int o = atomicAdd(&ovfB[0], 1); if (o < OVF_MAX) { ovfB[2 + 2*o] = d; ovfB[3 + 2*o] = s; } }
        }
    }
}

__global__ __launch_bounds__(256) void k_gatherG(const ushort* __restrict__ Ybf,
                                                 const int* __restrict__ deg,
                                                 const int* __restrict__ bucket,
                                                 const int* __restrict__ ovf,
                                                 const float* __restrict__ bias,
                                                 float* __restrict__ out, int N) {
    int tid = threadIdx.x;
    int w = tid >> 6, lane = tid & 63;
    int g = lane >> 3, c = lane & 7;
    int n = blockIdx.x * 4 + w;
    if (n >= N) return;
    int d = deg[n];
    int m = min(d, CAP);
    int boff = n * CAP;
    const uint4* Y16 = (const uint4*)Ybf;
    float acc[4][8];
#pragma unroll
    for (int ch = 0; ch < 4; ++ch)
#pragma unroll
        for (int j = 0; j < 8; ++j) acc[ch][j] = 0.f;
    int last = m - 1;
    for (int base = 0; base < m; base += 32) {
#pragma unroll
        for (int ch = 0; ch < 4; ++ch) {
            int jdx = base + ch * 8 + g;
            int s = bucket[boff + min(jdx, last)];
            uint4 qv = Y16[(long)s * 8 + c];
            if (jdx < m) {
                acc[ch][0] += __uint_as_float(qv.x << 16);
                acc[ch][1] += __uint_as_float(qv.x & 0xFFFF0000u);
                acc[ch][2] += __uint_as_float(qv.y << 16);
                acc[ch][3] += __uint_as_float(qv.y & 0xFFFF0000u);
                acc[ch][4] += __uint_as_float(qv.z << 16);
                acc[ch][5] += __uint_as_float(qv.z & 0xFFFF0000u);
                acc[ch][6] += __uint_as_float(qv.w << 16);
                acc[ch][7] += __uint_as_float(qv.w & 0xFFFF0000u);
            }
        }
    }
    if (d > CAP) {
        int no = ovf[0]; if (no > OVF_MAX) no = OVF_MAX;
        if (g == 0) {
            for (int i = 0; i < no; ++i) {
                if (ovf[2 + 2*i] == n) {
                    int s = ovf[3 + 2*i];
                    uint4 qv = Y16[(long)s * 8 + c];
                    acc[0][0] += __uint_as_float(qv.x << 16);
                    acc[0][1] += __uint_as_float(qv.x & 0xFFFF0000u);
                    acc[0][2] += __uint_as_float(qv.y << 16);
                    acc[0][3] += __uint_as_float(qv.y & 0xFFFF0000u);
                    acc[0][4] += __uint_as_float(qv.z << 16);
                    acc[0][5] += __uint_as_float(qv.z & 0xFFFF0000u);
                    acc[0][6] += __uint_as_float(qv.w << 16);
                    acc[0][7] += __uint_as_float(qv.w & 0xFFFF0000u);
                }
            }
        }
    }
#pragma unroll
    for (int j = 0; j < 8; ++j)
        acc[0][j] += (acc[1][j] + acc[2][j]) + acc[3][j];
#pragma unroll
    for (int j = 0; j < 8; ++j) {
        float v = acc[0][j];
        v += __shfl_xor(v, 8);
        v += __shfl_xor(v, 16);
        v += __shfl_xor(v, 32);
        acc[0][j] = v;
    }
    float sel = acc[0][0];
#pragma unroll
    for (int j = 1; j < 8; ++j) sel = (g == j) ? acc[0][j] : sel;
    int fw = c * 8 + g;
    float hv;
    if (d > 0) hv = sel / (float)d;
    else       hv = __uint_as_float(((uint)Ybf[(long)n * F + fw]) << 16);
    out[(long)n * F + fw] = fmaxf(hv + bias[fw], 0.0f);
}

// ---------- tier C: pure atomic (tiny ws) ----------
__global__ __launch_bounds__(256) void gcn_edge_scatter(const float* __restrict__ feature,
                                                        const int* __restrict__ esrc,
                                                        const int* __restrict__ edst,
                                                        float* __restrict__ agg,
                                                        float* __restrict__ cnt, int E) {
    int t = blockIdx.x * blockDim.x + threadIdx.x;
    int e = t >> 6, f = t & 63;
    if (e >= E) return;
    atomicAdd(&agg[(long)edst[e] * F + f], feature[(long)esrc[e] * F + f]);
    if (f == 0) atomicAdd(&cnt[edst[e]], 1.0f);
}
__global__ __launch_bounds__(256) void gcn_node_apply(const float* __restrict__ feature,
                                                      const float* __restrict__ W,
                                                      const float* __restrict__ bias,
                                                      const float* __restrict__ cnt,
                                                      float* __restrict__ inout, int N) {
    __shared__ float sWt[64 * 65];
    __shared__ float sh[4][64];
    int tid = threadIdx.x;
    for (int i = tid; i < 64 * 64; i += 256) {
        int fo = i >> 6, k = i & 63;
        sWt[k * 65 + fo] = W[i];
    }
    int w = tid >> 6, f = tid & 63;
    int n = blockIdx.x * 4 + w;
    float h = 0.0f;
    if (n < N) {
        float c = cnt[n];
        h = (c > 0.0f) ? inout[(long)n * F + f] / c : feature[(long)n * F + f];
    }
    sh[w][f] = h;
    __syncthreads();
    float acc = bias[f];
#pragma unroll
    for (int k = 0; k < 64; ++k) acc = fmaf(sh[w][k], sWt[k * 65 + f], acc);
    if (n < N) inout[(long)n * F + f] = fmaxf(acc, 0.0f);
}

extern "C" void kernel_launch(void* const* d_in, const int* in_sizes, int n_in,
                              void* d_out, int out_size, void* d_ws, size_t ws_size,
                              hipStream_t stream) {
    const float* feature = (const float*)d_in[0];
    const int*   esrc    = (const int*)d_in[1];
    const int*   edst    = (const int*)d_in[2];
    const float* W       = (const float*)d_in[3];
    const float* bias    = (const float*)d_in[4];

    int N = in_sizes[0] / F;   // 50000
    int E = in_sizes[1];       // 800000

    int G   = (N + 63) / 64;           // GEMM blocks (64 nodes each)
    int S   = (E + EB - 1) / EB;       // sort blocks
    int Q   = (N + QW - 1) / QW;       // quarters (782)
    int QP1 = Q + 1;

    auto align256 = [](size_t x) { return (x + 255) & ~(size_t)255; };
    size_t sz_ovf = align256((2 + 2 * (size_t)OVF_MAX) * sizeof(int));
    size_t sz_Y   = align256((size_t)N * F * sizeof(ushort));
    size_t sz_blk = align256((size_t)S * EB * sizeof(int));
    size_t sz_pfx = align256((size_t)S * QP1 * sizeof(int));
    size_t need_new = sz_ovf + sz_Y + sz_blk + sz_pfx;

    size_t sz_deg    = align256((size_t)N * sizeof(int));
    size_t sz_bucket = align256((size_t)N * CAP * sizeof(int));
    size_t need_mid  = sz_ovf + sz_Y + sz_deg + sz_bucket;

    if (ws_size >= need_new && N <= 65536) {   // 1024 bins + 24-bit src pack
        char* ws = (char*)d_ws;
        int*    ovfB   = (int*)ws;    ws += sz_ovf;
        ushort* Ybf    = (ushort*)ws; ws += sz_Y;
        int*    blkBuf = (int*)ws;    ws += sz_blk;
        int*    pfxTab = (int*)ws;
        float*  out    = (float*)d_out;

        k_work<<<G + S, 256, 0, stream>>>(feature, W, Ybf, esrc, edst,
                                          blkBuf, pfxTab, ovfB, N, E, G, QP1);
        k_bingather<<<Q, 512, 0, stream>>>(Ybf, blkBuf, pfxTab, ovfB,
                                           bias, out, N, S, QP1);
    } else if (ws_size >= need_mid) {
        char* ws = (char*)d_ws;
        int*    ovfB   = (int*)ws;    ws += sz_ovf;
        ushort* Ybf    = (ushort*)ws; ws += sz_Y;
        int*    deg    = (int*)ws;    ws += sz_deg;
        int*    bucket = (int*)ws;
        float*  out    = (float*)d_out;
        int n4 = (N + 3) / 4;
        int gE4 = (E + 1023) / 1024;

        k_gemm13<<<(N + 31) / 32, 256, 0, stream>>>(feature, W, Ybf, N, deg, n4, ovfB);
        k_scatter13<<<gE4, 256, 0, stream>>>(esrc, edst, deg, bucket, ovfB, E);
        k_gatherG<<<(N + 3) / 4, 256, 0, stream>>>(Ybf, deg, bucket, ovfB, bias, out, N);
    } else {
        float* agg = (float*)d_out;
        float* cnt = (float*)d_ws;
        hipMemsetAsync(agg, 0, (size_t)N * F * sizeof(float), stream);
        hipMemsetAsync(cnt, 0, (size_t)N * sizeof(float), stream);
        long total = (long)E * F;
        gcn_edge_scatter<<<(int)((total + 255) / 256), 256, 0, stream>>>(
            feature, esrc, edst, agg, cnt, E);
        gcn_node_apply<<<(N + 3) / 4, 256, 0, stream>>>(feature, W, bias, cnt, agg, N);
    }
}

// Round 25
// 53.013 us; speedup vs baseline: 1.0205x; 1.0205x over previous
//
#include <hip/hip_runtime.h>

// GCN layer: out = relu( G(feature) @ W^T + b ), G = mean over in-edges (or
// identity for isolated nodes).  N=50000, F=64, E=800000.
//
// GEMM commutes with the aggregation: G(feat)@W^T == G(feat@W^T).
// Round-23: EB 2048->4096 (16 edges/thread in sort role). Halves S (391->196)
// -> bin phase's scattered run reads halve and runs double in length (~5.2),
// pfxTab halves. GEMM role reverted to R21's proven 32-node form (R22's
// transposed variant was neutral-negative). k_bingather unchanged.
// Pipeline (2 dispatches): k_work (GEMM || quarter-sort) -> k_bingather.

#define F 64
#define CAP 48          // bucket slots per node
#define QW 64           // nodes per quarter (bin granularity)
#define EB 4096         // edges per sort block (16/thread)
#define OVF_MAX 32768

typedef unsigned int uint;
typedef unsigned short ushort;

__device__ __forceinline__ ushort f2bf(float x) {
    uint u = __float_as_uint(x);
    u += 0x7FFFu + ((u >> 16) & 1u);   // round-to-nearest-even
    return (ushort)(u >> 16);
}

// ---------- D1: role-split GEMM + quarter-sort ----------
__global__ __launch_bounds__(256) void k_work(const float* __restrict__ feature,
                                              const float* __restrict__ W,
                                              ushort* __restrict__ Ybf,
                                              const int* __restrict__ esrc,
                                              const int* __restrict__ edst,
                                              int* __restrict__ blkBuf,
                                              int* __restrict__ pfxTab,
                                              int* __restrict__ ovfB,
                                              int N, int E, int G, int QP1) {
    __shared__ alignas(16) char smem[29696];
    int tid = threadIdx.x, bid = blockIdx.x;
    if (bid == 0 && tid == 0) ovfB[0] = 0;

    if (bid < G) {
        // ---- GEMM role: 32 nodes/block (R21 proven form) ----
        float* sWt = (float*)smem;              // 64*76 floats = 19456B
        float* shh = (float*)(smem + 19456);    // 32*72 floats =  9216B
        for (int i = tid; i < 4096; i += 256) {
            int fo = i >> 6, k = i & 63;
            sWt[k * 76 + fo] = W[i];
        }
        int n0blk = bid * 32;
        for (int i = tid; i < 512; i += 256) {  // 32 rows x 16 float4
            int r = i >> 4, c4 = i & 15;
            int n = n0blk + r;
            float4 v = make_float4(0.f, 0.f, 0.f, 0.f);
            if (n < N) v = ((const float4*)feature)[(long)n * 16 + c4];
            *(float4*)&shh[r * 72 + c4 * 4] = v;
        }
        __syncthreads();
        int npair = tid >> 4, foq = tid & 15;
        int r0 = npair * 2, r1 = r0 + 1;
        float a0=0,a1=0,a2=0,a3=0,b0=0,b1=0,b2=0,b3=0;
#pragma unroll 8
        for (int k = 0; k < 64; ++k) {
            float hA = shh[r0 * 72 + k];
            float hB = shh[r1 * 72 + k];
            float4 wv = *(const float4*)&sWt[k * 76 + foq * 4];
            a0 = fmaf(hA, wv.x, a0); a1 = fmaf(hA, wv.y, a1);
            a2 = fmaf(hA, wv.z, a2); a3 = fmaf(hA, wv.w, a3);
            b0 = fmaf(hB, wv.x, b0); b1 = fmaf(hB, wv.y, b1);
            b2 = fmaf(hB, wv.z, b2); b3 = fmaf(hB, wv.w, b3);
        }
        int nA = n0blk + r0, nB = n0blk + r1;
        if (nA < N) ((ushort4*)Ybf)[(long)nA * 16 + foq] =
            make_ushort4(f2bf(a0), f2bf(a1), f2bf(a2), f2bf(a3));
        if (nB < N) ((ushort4*)Ybf)[(long)nB * 16 + foq] =
            make_ushort4(f2bf(b0), f2bf(b1), f2bf(b2), f2bf(b3));
    } else {
        // ---- sort role: 4096 edges binned by quarter (dst>>6), 16/thread ---
        int* cnt   = (int*)smem;                // 1024 ints
        int* pfx   = (int*)(smem + 4096);       // 1024 ints
        int* off   = (int*)(smem + 8192);       // 1024 ints
        int* sc    = (int*)(smem + 12288);      // 256 ints
        int* stage = (int*)(smem + 13312);      // 4096 ints (16KB)

        int b = bid - G;
        int ebase = b * EB;
        int d[16], s[16];
        int i0 = ebase + tid * 16;
        if (i0 + 15 < E) {
#pragma unroll
            for (int v4 = 0; v4 < 4; ++v4) {
                int4 dd = *(const int4*)(edst + i0 + v4 * 4);
                int4 ss = *(const int4*)(esrc + i0 + v4 * 4);
                d[v4*4+0]=dd.x; d[v4*4+1]=dd.y; d[v4*4+2]=dd.z; d[v4*4+3]=dd.w;
                s[v4*4+0]=ss.x; s[v4*4+1]=ss.y; s[v4*4+2]=ss.z; s[v4*4+3]=ss.w;
            }
        } else {
#pragma unroll
            for (int k = 0; k < 16; ++k) {
                int e = i0 + k;
                d[k] = (e < E) ? edst[e] : -1;
                s[k] = (e < E) ? esrc[e] : 0;
            }
        }
        for (int i = tid; i < 1024; i += 256) cnt[i] = 0;
        __syncthreads();
#pragma unroll
        for (int k = 0; k < 16; ++k)
            if (d[k] >= 0) atomicAdd(&cnt[d[k] >> 6], 1);
        __syncthreads();
        // two-level exclusive scan over 1024 bins (4 bins/thread)
        int b0i = tid * 4;
        int c0 = cnt[b0i], c1 = cnt[b0i+1], c2 = cnt[b0i+2], c3 = cnt[b0i+3];
        int s4 = c0 + c1 + c2 + c3;
        sc[tid] = s4;
        __syncthreads();
        for (int dd = 1; dd < 256; dd <<= 1) {
            int t = (tid >= dd) ? sc[tid - dd] : 0;
            __syncthreads();
            sc[tid] += t;
            __syncthreads();
        }
        int run = sc[tid] - s4;
        pfx[b0i]   = run; off[b0i]   = run; run += c0;
        pfx[b0i+1] = run; off[b0i+1] = run; run += c1;
        pfx[b0i+2] = run; off[b0i+2] = run; run += c2;
        pfx[b0i+3] = run; off[b0i+3] = run;
        __syncthreads();
#pragma unroll
        for (int k = 0; k < 16; ++k) {
            if (d[k] >= 0) {
                int q = d[k] >> 6;
                int sl = atomicAdd(&off[q], 1);
                stage[sl] = ((d[k] & 63) << 24) | s[k];   // N<=65536 (host guard)
            }
        }
        __syncthreads();
        int total = sc[255];
        for (int i = tid; i < total; i += 256)
            blkBuf[ebase + i] = stage[i];                 // coalesced dump
        for (int i = tid; i < QP1; i += 256)
            pfxTab[b * QP1 + i] = pfx[i];                 // bins >= Q hold total
    }
}

// ---------- D2: per-quarter bin (LDS) + gather-mean + bias + relu ----------
__global__ __launch_bounds__(512) void k_bingather(const ushort* __restrict__ Ybf,
                                                   const int* __restrict__ blkBuf,
                                                   const int* __restrict__ pfxTab,
                                                   int* __restrict__ ovfB,
                                                   const float* __restrict__ bias,
                                                   float* __restrict__ out,
                                                   int N, int S, int QP1) {
    __shared__ int dl[QW];
    __shared__ int bl[QW * CAP];   // 12.3KB
    int tid = threadIdx.x;
    int q   = blockIdx.x;          // quarter id: nodes q*64 .. q*64+63
    for (int i = tid; i < QW; i += 512) dl[i] = 0;
    __syncthreads();
    // bin: one thread per source block's run (exact entries, no filtering)
    for (int b = tid; b < S; b += 512) {
        int lo = pfxTab[b * QP1 + q];
        int hi = pfxTab[b * QP1 + q + 1];
        for (int i = lo; i < hi; ++i) {
            int v = blkBuf[b * EB + i];
            int ll = ((uint)v) >> 24;
            int s = v & 0xFFFFFF;
            int r = atomicAdd(&dl[ll], 1);
            if (r < CAP) bl[ll * CAP + r] = s;
            else { int o = atomicAdd(&ovfB[0], 1);
                   if (o < OVF_MAX) { ovfB[2 + 2*o] = q * QW + ll; ovfB[3 + 2*o] = s; } }
        }
    }
    __syncthreads();
    // gather: 8 waves x 8 passes = 64 nodes; 16-edge stride, 2 chains
    int wv = tid >> 6, lane = tid & 63;
    int g = lane >> 3, c = lane & 7;
    const uint4* Y16 = (const uint4*)Ybf;
    for (int pass = 0; pass < QW / 8; ++pass) {
        int ll = pass * 8 + wv;
        int n = q * QW + ll;
        if (n < N) {
            int d = dl[ll];
            int m = min(d, CAP);
            float acc[2][8];
#pragma unroll
            for (int ch = 0; ch < 2; ++ch)
#pragma unroll
                for (int j = 0; j < 8; ++j) acc[ch][j] = 0.f;
            int last = m - 1;
            for (int base = 0; base < m; base += 16) {
#pragma unroll
                for (int ch = 0; ch < 2; ++ch) {
                    int jdx = base + ch * 8 + g;
                    int s = bl[ll * CAP + min(jdx, last)];
                    uint4 qv = Y16[(long)s * 8 + c];
                    if (jdx < m) {
                        acc[ch][0] += __uint_as_float(qv.x << 16);
                        acc[ch][1] += __uint_as_float(qv.x & 0xFFFF0000u);
                        acc[ch][2] += __uint_as_float(qv.y << 16);
                        acc[ch][3] += __uint_as_float(qv.y & 0xFFFF0000u);
                        acc[ch][4] += __uint_as_float(qv.z << 16);
                        acc[ch][5] += __uint_as_float(qv.z & 0xFFFF0000u);
                        acc[ch][6] += __uint_as_float(qv.w << 16);
                        acc[ch][7] += __uint_as_float(qv.w & 0xFFFF0000u);
                    }
                }
            }
            if (d > CAP) {   // overflow tail (empty for this input)
                int no = ovfB[0]; if (no > OVF_MAX) no = OVF_MAX;
                if (g == 0) {
                    for (int i = 0; i < no; ++i) {
                        if (ovfB[2 + 2*i] == n) {
                            int s = ovfB[3 + 2*i];
                            uint4 qv = Y16[(long)s * 8 + c];
                            acc[0][0] += __uint_as_float(qv.x << 16);
                            acc[0][1] += __uint_as_float(qv.x & 0xFFFF0000u);
                            acc[0][2] += __uint_as_float(qv.y << 16);
                            acc[0][3] += __uint_as_float(qv.y & 0xFFFF0000u);
                            acc[0][4] += __uint_as_float(qv.z << 16);
                            acc[0][5] += __uint_as_float(qv.z & 0xFFFF0000u);
                            acc[0][6] += __uint_as_float(qv.w << 16);
                            acc[0][7] += __uint_as_float(qv.w & 0xFFFF0000u);
                        }
                    }
                }
            }
#pragma unroll
            for (int j = 0; j < 8; ++j)
                acc[0][j] += acc[1][j];
#pragma unroll
            for (int j = 0; j < 8; ++j) {
                float v = acc[0][j];
                v += __shfl_xor(v, 8);
                v += __shfl_xor(v, 16);
                v += __shfl_xor(v, 32);
                acc[0][j] = v;
            }
            float sel = acc[0][0];
#pragma unroll
            for (int j = 1; j < 8; ++j) sel = (g == j) ? acc[0][j] : sel;
            int fw = c * 8 + g;
            float hv;
            if (d > 0) hv = sel / (float)d;
            else       hv = __uint_as_float(((uint)Ybf[(long)n * F + fw]) << 16);
            out[(long)n * F + fw] = fmaxf(hv + bias[fw], 0.0f);
        }
    }
}

// ================= mid-tier (R13/R16 proven) ==========================
__global__ __launch_bounds__(256) void k_gemm13(const float* __restrict__ feature,
                                                const float* __restrict__ W,
                                                ushort* __restrict__ Ybf, int N,
                                                int* __restrict__ deg, int n4,
                                                int* __restrict__ ovfB) {
    {
        int gt = blockIdx.x * 256 + threadIdx.x;
        if (gt == 0) ovfB[0] = 0;
        for (int i = gt; i < n4; i += gridDim.x * 256)
            ((int4*)deg)[i] = make_int4(0, 0, 0, 0);
    }
    __shared__ float sWt[64 * 76];
    __shared__ float shh[32 * 72];
    int tid = threadIdx.x;
    for (int i = tid; i < 4096; i += 256) {
        int fo = i >> 6, k = i & 63;
        sWt[k * 76 + fo] = W[i];
    }
    int n0blk = blockIdx.x * 32;
    for (int i = tid; i < 512; i += 256) {
        int r = i >> 4, c4 = i & 15;
        int n = n0blk + r;
        float4 v = make_float4(0.f, 0.f, 0.f, 0.f);
        if (n < N) v = ((const float4*)feature)[(long)n * 16 + c4];
        *(float4*)&shh[r * 72 + c4 * 4] = v;
    }
    __syncthreads();
    int npair = tid >> 4, foq = tid & 15;
    int r0 = npair * 2, r1 = r0 + 1;
    float a0=0,a1=0,a2=0,a3=0,b0=0,b1=0,b2=0,b3=0;
#pragma unroll 8
    for (int k = 0; k < 64; ++k) {
        float hA = shh[r0 * 72 + k];
        float hB = shh[r1 * 72 + k];
        float4 wv = *(const float4*)&sWt[k * 76 + foq * 4];
        a0 = fmaf(hA, wv.x, a0); a1 = fmaf(hA, wv.y, a1);
        a2 = fmaf(hA, wv.z, a2); a3 = fmaf(hA, wv.w, a3);
        b0 = fmaf(hB, wv.x, b0); b1 = fmaf(hB, wv.y, b1);
        b2 = fmaf(hB, wv.z, b2); b3 = fmaf(hB, wv.w, b3);
    }
    int nA = n0blk + r0, nB = n0blk + r1;
    if (nA < N) ((ushort4*)Ybf)[(long)nA * 16 + foq] =
        make_ushort4(f2bf(a0), f2bf(a1), f2bf(a2), f2bf(a3));
    if (nB < N) ((ushort4*)Ybf)[(long)nB * 16 + foq] =
        make_ushort4(f2bf(b0), f2bf(b1), f2bf(b2), f2bf(b3));
}

__global__ __launch_bounds__(256) void k_scatter13(const int* __restrict__ esrc,
                                                   const int* __restrict__ edst,
                                                   int* __restrict__ deg,
                                                   int* __restrict__ bucket,
                                                   int* __restrict__ ovfB, int E) {
    int base = (blockIdx.x * 256 + threadIdx.x) * 4;
    if (base + 3 < E) {
        int4 d4 = *(const int4*)(edst + base);
        int4 s4 = *(const int4*)(esrc + base);
        int r0 = atomicAdd(&deg[d4.x], 1);
        int r1 = atomicAdd(&deg[d4.y], 1);
        int r2 = atomicAdd(&deg[d4.z], 1);
        int r3 = atomicAdd(&deg[d4.w], 1);
        if (r0 < CAP) bucket[d4.x * CAP + r0] = s4.x;
        else { int o = atomicAdd(&ovfB[0], 1); if (o < OVF_MAX) { ovfB[2 + 2*o] = d4.x; ovfB[3 + 2*o] = s4.x; } }
        if (r1 < CAP) bucket[d4.y * CAP + r1] = s4.y;
        else { int o = atomicAdd(&ovfB[0], 1); if (o < OVF_MAX) { ovfB[2 + 2*o] = d4.y; ovfB[3 + 2*o] = s4.y; } }
        if (r2 < CAP) bucket[d4.z * CAP + r2] = s4.z;
        else { int o = atomicAdd(&ovfB[0], 1); if (o < OVF_MAX) { ovfB[2 + 2*o] = d4.z; ovfB[3 + 2*o] = s4.z; } }
        if (r3 < CAP) bucket[d4.w * CAP + r3] = s4.w;
        else { int o = atomicAdd(&ovfB[0], 1); if (o < OVF_MAX) { ovfB[2 + 2*o] = d4.w; ovfB[3 + 2*o] = s4.w; } }
    } else {
        for (int e = base; e < E; ++e) {
            int d = edst[e], s = esrc[e];
            int r = atomicAdd(&deg[d], 1);
            if (r < CAP) bucket[d * CAP + r] = s;
            else { int o = atomicAdd(&ovfB[0], 1); if (o < OVF_MAX) { ovfB[2 + 2*o] = d; ovfB[3 + 2*o] = s; } }
        }
    }
}

__global__ __launch_bounds__(256) void k_gatherG(const ushort* __restrict__ Ybf,
                                                 const int* __restrict__ deg,
                                                 const int* __restrict__ bucket,
                                                 const int* __restrict__ ovf,
                                                 const float* __restrict__ bias,
                                                 float* __restrict__ out, int N) {
    int tid = threadIdx.x;
    int w = tid >> 6, lane = tid & 63;
    int g = lane >> 3, c = lane & 7;
    int n = blockIdx.x * 4 + w;
    if (n >= N) return;
    int d = deg[n];
    int m = min(d, CAP);
    int boff = n * CAP;
    const uint4* Y16 = (const uint4*)Ybf;
    float acc[4][8];
#pragma unroll
    for (int ch = 0; ch < 4; ++ch)
#pragma unroll
        for (int j = 0; j < 8; ++j) acc[ch][j] = 0.f;
    int last = m - 1;
    for (int base = 0; base < m; base += 32) {
#pragma unroll
        for (int ch = 0; ch < 4; ++ch) {
            int jdx = base + ch * 8 + g;
            int s = bucket[boff + min(jdx, last)];
            uint4 qv = Y16[(long)s * 8 + c];
            if (jdx < m) {
                acc[ch][0] += __uint_as_float(qv.x << 16);
                acc[ch][1] += __uint_as_float(qv.x & 0xFFFF0000u);
                acc[ch][2] += __uint_as_float(qv.y << 16);
                acc[ch][3] += __uint_as_float(qv.y & 0xFFFF0000u);
                acc[ch][4] += __uint_as_float(qv.z << 16);
                acc[ch][5] += __uint_as_float(qv.z & 0xFFFF0000u);
                acc[ch][6] += __uint_as_float(qv.w << 16);
                acc[ch][7] += __uint_as_float(qv.w & 0xFFFF0000u);
            }
        }
    }
    if (d > CAP) {
        int no = ovf[0]; if (no > OVF_MAX) no = OVF_MAX;
        if (g == 0) {
            for (int i = 0; i < no; ++i) {
                if (ovf[2 + 2*i] == n) {
                    int s = ovf[3 + 2*i];
                    uint4 qv = Y16[(long)s * 8 + c];
                    acc[0][0] += __uint_as_float(qv.x << 16);
                    acc[0][1] += __uint_as_float(qv.x & 0xFFFF0000u);
                    acc[0][2] += __uint_as_float(qv.y << 16);
                    acc[0][3] += __uint_as_float(qv.y & 0xFFFF0000u);
                    acc[0][4] += __uint_as_float(qv.z << 16);
                    acc[0][5] += __uint_as_float(qv.z & 0xFFFF0000u);
                    acc[0][6] += __uint_as_float(qv.w << 16);
                    acc[0][7] += __uint_as_float(qv.w & 0xFFFF0000u);
                }
            }
        }
    }
#pragma unroll
    for (int j = 0; j < 8; ++j)
        acc[0][j] += (acc[1][j] + acc[2][j]) + acc[3][j];
#pragma unroll
    for (int j = 0; j < 8; ++j) {
        float v = acc[0][j];
        v += __shfl_xor(v, 8);
        v += __shfl_xor(v, 16);
        v += __shfl_xor(v, 32);
        acc[0][j] = v;
    }
    float sel = acc[0][0];
#pragma unroll
    for (int j = 1; j < 8; ++j) sel = (g == j) ? acc[0][j] : sel;
    int fw = c * 8 + g;
    float hv;
    if (d > 0) hv = sel / (float)d;
    else       hv = __uint_as_float(((uint)Ybf[(long)n * F + fw]) << 16);
    out[(long)n * F + fw] = fmaxf(hv + bias[fw], 0.0f);
}

// ---------- tier C: pure atomic (tiny ws) ----------
__global__ __launch_bounds__(256) void gcn_edge_scatter(const float* __restrict__ feature,
                                                        const int* __restrict__ esrc,
                                                        const int* __restrict__ edst,
                                                        float* __restrict__ agg,
                                                        float* __restrict__ cnt, int E) {
    int t = blockIdx.x * blockDim.x + threadIdx.x;
    int e = t >> 6, f = t & 63;
    if (e >= E) return;
    atomicAdd(&agg[(long)edst[e] * F + f], feature[(long)esrc[e] * F + f]);
    if (f == 0) atomicAdd(&cnt[edst[e]], 1.0f);
}
__global__ __launch_bounds__(256) void gcn_node_apply(const float* __restrict__ feature,
                                                      const float* __restrict__ W,
                                                      const float* __restrict__ bias,
                                                      const float* __restrict__ cnt,
                                                      float* __restrict__ inout, int N) {
    __shared__ float sWt[64 * 65];
    __shared__ float sh[4][64];
    int tid = threadIdx.x;
    for (int i = tid; i < 64 * 64; i += 256) {
        int fo = i >> 6, k = i & 63;
        sWt[k * 65 + fo] = W[i];
    }
    int w = tid >> 6, f = tid & 63;
    int n = blockIdx.x * 4 + w;
    float h = 0.0f;
    if (n < N) {
        float c = cnt[n];
        h = (c > 0.0f) ? inout[(long)n * F + f] / c : feature[(long)n * F + f];
    }
    sh[w][f] = h;
    __syncthreads();
    float acc = bias[f];
#pragma unroll
    for (int k = 0; k < 64; ++k) acc = fmaf(sh[w][k], sWt[k * 65 + f], acc);
    if (n < N) inout[(long)n * F + f] = fmaxf(acc, 0.0f);
}

extern "C" void kernel_launch(void* const* d_in, const int* in_sizes, int n_in,
                              void* d_out, int out_size, void* d_ws, size_t ws_size,
                              hipStream_t stream) {
    const float* feature = (const float*)d_in[0];
    const int*   esrc    = (const int*)d_in[1];
    const int*   edst    = (const int*)d_in[2];
    const float* W       = (const float*)d_in[3];
    const float* bias    = (const float*)d_in[4];

    int N = in_sizes[0] / F;   // 50000
    int E = in_sizes[1];       // 800000

    int G   = (N + 31) / 32;           // GEMM blocks
    int S   = (E + EB - 1) / EB;       // sort blocks (196)
    int Q   = (N + QW - 1) / QW;       // quarters (782)
    int QP1 = Q + 1;

    auto align256 = [](size_t x) { return (x + 255) & ~(size_t)255; };
    size_t sz_ovf = align256((2 + 2 * (size_t)OVF_MAX) * sizeof(int));
    size_t sz_Y   = align256((size_t)N * F * sizeof(ushort));
    size_t sz_blk = align256((size_t)S * EB * sizeof(int));
    size_t sz_pfx = align256((size_t)S * QP1 * sizeof(int));
    size_t need_new = sz_ovf + sz_Y + sz_blk + sz_pfx;

    size_t sz_deg    = align256((size_t)N * sizeof(int));
    size_t sz_bucket = align256((size_t)N * CAP * sizeof(int));
    size_t need_mid  = sz_ovf + sz_Y + sz_deg + sz_bucket;

    if (ws_size >= need_new && N <= 65536) {   // 1024 bins + 24-bit src pack
        char* ws = (char*)d_ws;
        int*    ovfB   = (int*)ws;    ws += sz_ovf;
        ushort* Ybf    = (ushort*)ws; ws += sz_Y;
        int*    blkBuf = (int*)ws;    ws += sz_blk;
        int*    pfxTab = (int*)ws;
        float*  out    = (float*)d_out;

        k_work<<<G + S, 256, 0, stream>>>(feature, W, Ybf, esrc, edst,
                                          blkBuf, pfxTab, ovfB, N, E, G, QP1);
        k_bingather<<<Q, 512, 0, stream>>>(Ybf, blkBuf, pfxTab, ovfB,
                                           bias, out, N, S, QP1);
    } else if (ws_size >= need_mid) {
        char* ws = (char*)d_ws;
        int*    ovfB   = (int*)ws;    ws += sz_ovf;
        ushort* Ybf    = (ushort*)ws; ws += sz_Y;
        int*    deg    = (int*)ws;    ws += sz_deg;
        int*    bucket = (int*)ws;
        float*  out    = (float*)d_out;
        int n4 = (N + 3) / 4;
        int gE4 = (E + 1023) / 1024;

        k_gemm13<<<(N + 31) / 32, 256, 0, stream>>>(feature, W, Ybf, N, deg, n4, ovfB);
        k_scatter13<<<gE4, 256, 0, stream>>>(esrc, edst, deg, bucket, ovfB, E);
        k_gatherG<<<(N + 3) / 4, 256, 0, stream>>>(Ybf, deg, bucket, ovfB, bias, out, N);
    } else {
        float* agg = (float*)d_out;
        float* cnt = (float*)d_ws;
        hipMemsetAsync(agg, 0, (size_t)N * F * sizeof(float), stream);
        hipMemsetAsync(cnt, 0, (size_t)N * sizeof(float), stream);
        long total = (long)E * F;
        gcn_edge_scatter<<<(int)((total + 255) / 256), 256, 0, stream>>>(
            feature, esrc, edst, agg, cnt, E);
        gcn_node_apply<<<(N + 3) / 4, 256, 0, stream>>>(feature, W, bias, cnt, agg, N);
    }
}